// Round 6
// baseline (869.412 us; speedup 1.0000x reference)
//
#include <hip/hip_runtime.h>
#include <stdint.h>

typedef __attribute__((ext_vector_type(8))) short short8;
typedef __attribute__((ext_vector_type(4))) float f32x4;

#define SCAN_TILE 4096

__device__ __forceinline__ float bf2f(unsigned short u) {
  union { unsigned int i; float f; } v;
  v.i = ((unsigned int)u) << 16;
  return v.f;
}
__device__ __forceinline__ unsigned short f2bf(float f) {
  union { float f; unsigned int i; } v;
  v.f = f;
  unsigned int u = v.i;
  return (unsigned short)((u + 0x7FFFu + ((u >> 16) & 1u)) >> 16);
}
__device__ __forceinline__ unsigned int pack2(float a, float b) {
  return (unsigned int)f2bf(a) | ((unsigned int)f2bf(b) << 16);
}
__device__ __forceinline__ void add2(float& a, float& b, unsigned int v) {
  a += bf2f((unsigned short)(v & 0xffff));
  b += bf2f((unsigned short)(v >> 16));
}

// ---------------------------------------------------------------------------
// MFMA fragment layout for [rows, K=128] bf16 matrices.
// chunk = (row/16)*4 + (k/32), each chunk = 1KB (64 lanes x 16B).
// slot within chunk = (row%16) + 16*((k%32)/8); (k%8) indexes inside 16B.
// A wave load of one fragment = uint4 at [chunk*64 + lane] -> 1KB coalesced.
// ---------------------------------------------------------------------------
__device__ __forceinline__ size_t fragS128(int row, int k) {
  return ((size_t)(row >> 4) * 4 + (size_t)(k >> 5)) * 512
       + (size_t)((((row & 15) + (((k >> 3) & 3) << 4)) << 3) + (k & 7));
}

// ---------------------------------------------------------------------------
// Weight transposes (fp32 -> bf16, [K,N] -> frag128 split lo/hi) in one launch.
// ---------------------------------------------------------------------------
__global__ __launch_bounds__(256) void build_wt_all(
    const float* __restrict__ Wl1ui, const float* __restrict__ Wr1ui,
    const float* __restrict__ Wl1iu, const float* __restrict__ Wr1iu,
    const float* __restrict__ Wl2ui, const float* __restrict__ Wr2ui,
    const float* __restrict__ Wl2iu, const float* __restrict__ Wr2iu,
    unsigned short* __restrict__ T1ui_l, unsigned short* __restrict__ T1ui_h,
    unsigned short* __restrict__ T1iu_l, unsigned short* __restrict__ T1iu_h,
    unsigned short* __restrict__ T2lui_l, unsigned short* __restrict__ T2lui_h,
    unsigned short* __restrict__ T2rui_l, unsigned short* __restrict__ T2rui_h,
    unsigned short* __restrict__ T2liu_l, unsigned short* __restrict__ T2liu_h,
    unsigned short* __restrict__ T2riu_l, unsigned short* __restrict__ T2riu_h)
{
  int idx = blockIdx.x * 256 + threadIdx.x;
  const float *W1, *W2;
  unsigned short *lo, *hi;
  int N, rel;
  if (idx < 65536)       { W1 = Wl1ui; W2 = Wr1ui;          lo = T1ui_l;  hi = T1ui_h;  N = 256; rel = idx; }
  else if (idx < 131072) { W1 = Wl1iu; W2 = Wr1iu;          lo = T1iu_l;  hi = T1iu_h;  N = 256; rel = idx - 65536; }
  else if (idx < 163840) { W1 = Wl2ui; W2 = Wl2ui + 128*128; lo = T2lui_l; hi = T2lui_h; N = 128; rel = idx - 131072; }
  else if (idx < 196608) { W1 = Wr2ui; W2 = Wr2ui + 128*128; lo = T2rui_l; hi = T2rui_h; N = 128; rel = idx - 163840; }
  else if (idx < 229376) { W1 = Wl2iu; W2 = Wl2iu + 128*128; lo = T2liu_l; hi = T2liu_h; N = 128; rel = idx - 196608; }
  else                   { W1 = Wr2iu; W2 = Wr2iu + 128*128; lo = T2riu_l; hi = T2riu_h; N = 128; rel = idx - 229376; }
  int n = rel >> 8;        // output-col index (B-frag row)
  int k = rel & 255;       // concat K index
  float v = (k < 128) ? W1[(size_t)k * N + n] : W2[(size_t)(k - 128) * N + n];
  if (k < 128) lo[fragS128(n, k)] = f2bf(v);
  else         hi[fragS128(n, k - 128)] = f2bf(v);
}

// ---------------------------------------------------------------------------
// Streaming fp32 -> bf16 frag128 conversion of self-features (x_item, x_user).
// ---------------------------------------------------------------------------
__global__ __launch_bounds__(256) void conv_x(
    const float* __restrict__ xu, const float* __restrict__ xi,
    uint4* __restrict__ XfI, uint4* __restrict__ XfU,
    int NI, int NU, int MI, int MU)
{
  int u = blockIdx.x * 256 + threadIdx.x;
  int unitsI = MI * 16;
  const float* x; uint4* Xf; int M; int rel;
  if (u < unitsI) { x = xi; Xf = XfI; M = NI; rel = u; }
  else {
    rel = u - unitsI;
    if (rel >= MU * 16) return;
    x = xu; Xf = XfU; M = NU;
  }
  int c = rel >> 6;                      // chunk
  int s = rel & 63;                      // 16B slot in chunk
  int row = ((c >> 2) << 4) + (s & 15);
  int k = ((c & 3) << 5) + ((s >> 4) << 3);
  uint4 o = make_uint4(0u, 0u, 0u, 0u);
  if (row < M) {
    f32x4 a = *(const f32x4*)(x + (size_t)row * 128 + k);
    f32x4 b = *(const f32x4*)(x + (size_t)row * 128 + k + 4);
    o.x = pack2(a[0], a[1]); o.y = pack2(a[2], a[3]);
    o.z = pack2(b[0], b[1]); o.w = pack2(b[2], b[3]);
  }
  Xf[rel] = o;
}

// ---------------------------------------------------------------------------
// CSR build over COMBINED node space (items [0,NI), users [NI,NI+NU)).
// ---------------------------------------------------------------------------
__global__ __launch_bounds__(256) void hist(
    const int* __restrict__ esrc, const int* __restrict__ edst,
    int* __restrict__ cntAll, int NI, int E)
{
  int e = blockIdx.x * 256 + threadIdx.x;
  if (e >= E) return;
  atomicAdd(&cntAll[edst[e]], 1);
  atomicAdd(&cntAll[NI + esrc[e]], 1);
}

__global__ __launch_bounds__(256) void scan_p1(
    const int* __restrict__ cnt, int* __restrict__ tileSums, int NA)
{
  __shared__ int red[256];
  int b = blockIdx.x, t = threadIdx.x;
  int base = b * SCAN_TILE;
  int s = 0;
  for (int i = t; i < SCAN_TILE; i += 256) {
    int g = base + i;
    if (g < NA) s += cnt[g];
  }
  red[t] = s;
  __syncthreads();
  for (int d = 128; d > 0; d >>= 1) {
    if (t < d) red[t] += red[t + d];
    __syncthreads();
  }
  if (t == 0) tileSums[b] = red[0];
}

__global__ __launch_bounds__(256) void scan_p2(
    int* __restrict__ tileSums, int nTiles, int* __restrict__ offEnd)
{
  __shared__ int buf[256];
  int t = threadIdx.x;
  int v = (t < nTiles) ? tileSums[t] : 0;
  buf[t] = v;
  __syncthreads();
  for (int d = 1; d < 256; d <<= 1) {
    int x = (t >= d) ? buf[t - d] : 0;
    __syncthreads();
    buf[t] += x;
    __syncthreads();
  }
  if (t < nTiles) tileSums[t] = buf[t] - v;   // exclusive
  if (t == nTiles - 1) *offEnd = buf[t];      // grand total -> offAll[NA]
}

__global__ __launch_bounds__(256) void scan_p3(
    const int* __restrict__ cnt, const int* __restrict__ tileSums,
    int* __restrict__ off, int NA)
{
  __shared__ int red[256];
  int b = blockIdx.x, t = threadIdx.x;
  int base = b * SCAN_TILE + t * 16;
  int loc[16];
  int s = 0;
#pragma unroll
  for (int i = 0; i < 16; ++i) {
    int g = base + i;
    loc[i] = (g < NA) ? cnt[g] : 0;
    s += loc[i];
  }
  red[t] = s;
  __syncthreads();
  for (int d = 1; d < 256; d <<= 1) {
    int x = (t >= d) ? red[t - d] : 0;
    __syncthreads();
    red[t] += x;
    __syncthreads();
  }
  int run = tileSums[b] + red[t] - s;  // exclusive base for this thread
#pragma unroll
  for (int i = 0; i < 16; ++i) {
    int g = base + i;
    if (g < NA) off[g] = run;
    run += loc[i];
  }
}

__global__ __launch_bounds__(256) void fill_idx(
    const int* __restrict__ esrc, const int* __restrict__ edst,
    const int* __restrict__ offAll, int* __restrict__ curAll,
    int* __restrict__ idxAll, int NI, int E)
{
  int e = blockIdx.x * 256 + threadIdx.x;
  if (e >= E) return;
  int s = esrc[e], d = edst[e];
  int pI = offAll[d] + atomicAdd(&curAll[d], 1);
  idxAll[pI] = s;                     // item d aggregates user rows
  int pU = offAll[NI + s] + atomicAdd(&curAll[NI + s], 1);
  idxAll[pU] = d;                     // user s aggregates item rows
}

// ---------------------------------------------------------------------------
// Layer-1 neighbor mean, one 32-lane HALF per node (2 nodes/wave).
// ---------------------------------------------------------------------------
__global__ __launch_bounds__(256) void build_mean(
    const float* __restrict__ xu, const float* __restrict__ xi,
    const int* __restrict__ idxAll, const int* __restrict__ offAll,
    unsigned short* __restrict__ MfI, unsigned short* __restrict__ MfU,
    int NI, int NA)
{
  int w2 = (blockIdx.x * 256 + threadIdx.x) >> 6;   // wave id
  int l = threadIdx.x & 63;
  int h = l >> 5;                          // half id (0/1)
  int lh = l & 31;                         // lane within half
  int node = w2 * 2 + h;
  if (node >= NA) return;
  bool isItem = (node < NI);
  const float* xo = isItem ? xu : xi;      // neighbor features
  unsigned short* Mf = isItem ? MfI : MfU;
  int n = isItem ? node : (node - NI);
  int s = offAll[node], e = offAll[node + 1];

  f32x4 acc = (f32x4){0.f, 0.f, 0.f, 0.f};
  int j = s;
  for (; j + 1 < e; j += 2) {              // 2 rows in flight per half
    int g0 = idxAll[j];
    int g1 = idxAll[j + 1];
    f32x4 v0 = *(const f32x4*)(xo + (size_t)g0 * 128 + lh * 4);
    f32x4 v1 = *(const f32x4*)(xo + (size_t)g1 * 128 + lh * 4);
    acc += v0 + v1;
  }
  if (j < e) {
    int g = idxAll[j];
    acc += *(const f32x4*)(xo + (size_t)g * 128 + lh * 4);
  }

  float inv = 1.0f / (float)max(e - s, 1);
  uint2 o;
  o.x = pack2(acc[0] * inv, acc[1] * inv);
  o.y = pack2(acc[2] * inv, acc[3] * inv);
  *(uint2*)(Mf + fragS128(n, lh * 4)) = o;
}

// ---------------------------------------------------------------------------
// Layer-2 aggregation: one 16-lane QUARTER per node (4 nodes/wave).
// ---------------------------------------------------------------------------
__global__ __launch_bounds__(256) void seg_mean(
    const unsigned int* __restrict__ pU, const unsigned int* __restrict__ pI,
    const int* __restrict__ idxAll, const int* __restrict__ offAll,
    unsigned int* __restrict__ m2I, unsigned int* __restrict__ m2U,
    int NI, int NA)
{
  int w4 = (blockIdx.x * 256 + threadIdx.x) >> 6;
  int l = threadIdx.x & 63;
  int q = l >> 4;                          // quarter id (0..3)
  int lq = l & 15;                         // lane within quarter
  int node = w4 * 4 + q;
  if (node >= NA) return;
  bool isItem = (node < NI);
  const unsigned int* p = isItem ? pU : pI;
  unsigned int* m2 = isItem ? m2I : m2U;
  int n = isItem ? node : (node - NI);
  int s = offAll[node], e = offAll[node + 1];

  float a0 = 0.f, a1 = 0.f, a2 = 0.f, a3 = 0.f,
        a4 = 0.f, a5 = 0.f, a6 = 0.f, a7 = 0.f;

  int j = s;
  for (; j + 1 < e; j += 2) {              // 2 rows in flight per quarter
    int g0 = idxAll[j];
    int g1 = idxAll[j + 1];
    uint4 v0 = *(const uint4*)(p + (size_t)g0 * 64 + lq * 4);
    uint4 v1 = *(const uint4*)(p + (size_t)g1 * 64 + lq * 4);
    add2(a0, a1, v0.x); add2(a2, a3, v0.y); add2(a4, a5, v0.z); add2(a6, a7, v0.w);
    add2(a0, a1, v1.x); add2(a2, a3, v1.y); add2(a4, a5, v1.z); add2(a6, a7, v1.w);
  }
  if (j < e) {
    int g = idxAll[j];
    uint4 v = *(const uint4*)(p + (size_t)g * 64 + lq * 4);
    add2(a0, a1, v.x); add2(a2, a3, v.y); add2(a4, a5, v.z); add2(a6, a7, v.w);
  }

  float inv = 1.0f / (float)max(e - s, 1);
  uint4 o;
  o.x = pack2(a0 * inv, a1 * inv);
  o.y = pack2(a2 * inv, a3 * inv);
  o.z = pack2(a4 * inv, a5 * inv);
  o.w = pack2(a6 * inv, a7 * inv);
  *(uint4*)(m2 + (size_t)n * 64 + lq * 4) = o;
}

// ---------------------------------------------------------------------------
// Flat GEMM with LDS-staged B, K = 128+128 (split frag128 operands).
// B staged one K-half (32 KB) at a time into LDS (linear frag order, no
// conflicts); A fragments stream from global (coalesced 1KB wave loads).
// 3 barriers per block total (not per K-step). A k0=0 fragments are
// prefetched before each staging barrier so HBM latency hides under staging.
// Two GEMMs (item+user) merged per launch: block-range selects param set.
// Block = 128 rows x 128 cols, 4 waves 2x2, 64x64 per wave.
// MFMA operands swapped (mfma(b,a,acc)) -> lane holds row=lane&15, 4
// consecutive cols per quad -> vectorized stores.
// ---------------------------------------------------------------------------
struct GemmP {
  const unsigned short* Alo; const unsigned short* Ahi;
  const unsigned short* Blo; const unsigned short* Bhi;
  const float* bias;
  const unsigned short* Madd;   // [M,128] row-major or null
  void* outp; unsigned short* outHi;
  int M;
};

__global__ __launch_bounds__(256, 4) void gemm_flat(
    GemmP P0, GemmP P1, int rb0,
    int outF32, int outFrag, int N, int doRelu)
{
  __shared__ uint4 lB[2048];   // 32 KB: one K-half of a 128-col strip

  const int bx = blockIdx.x;
  const bool first = (bx < rb0);
  GemmP P = first ? P0 : P1;
  const int mb = first ? bx : bx - rb0;

  const int tid = threadIdx.x;
  const int lane = tid & 63;
  const int wave = tid >> 6;
  const int m0 = mb * 128 + (wave >> 1) * 64;          // wave's first row
  const int nBase = blockIdx.y * 128;
  const int n0 = nBase + (wave & 1) * 64;              // wave's first col
  const int r16 = lane & 15;
  const int quad = lane >> 4;
  const int cgl = (wave & 1) * 4;                      // wave's first local col-group

  const uint4* AL = (const uint4*)P.Alo;
  const uint4* AH = (const uint4*)P.Ahi;
  const uint4* BL = (const uint4*)P.Blo + (size_t)(nBase >> 4) * 256;
  const uint4* BH = (const uint4*)P.Bhi + (size_t)(nBase >> 4) * 256;
  const size_t aB = (size_t)(m0 >> 4) * 256 + lane;

  f32x4 acc[4][4];
#pragma unroll
  for (int i = 0; i < 4; ++i)
#pragma unroll
    for (int j = 0; j < 4; ++j) acc[i][j] = (f32x4){0.f, 0.f, 0.f, 0.f};

  // ---- lo half ----
  short8 avp[4];
#pragma unroll
  for (int g = 0; g < 4; ++g) {          // prefetch A k0=0 (overlaps staging)
    uint4 t = AL[aB + (size_t)(g * 4) * 64];
    avp[g] = *(const short8*)&t;
  }
#pragma unroll
  for (int i = 0; i < 8; ++i)            // stage B-lo: linear 32 KB copy
    lB[i * 256 + tid] = BL[i * 256 + tid];
  __syncthreads();

#pragma unroll
  for (int k0 = 0; k0 < 4; ++k0) {
    short8 av[4], bv[4];
#pragma unroll
    for (int g = 0; g < 4; ++g) {
      if (k0 == 0) av[g] = avp[g];
      else {
        uint4 t = AL[aB + (size_t)(g * 4 + k0) * 64];
        av[g] = *(const short8*)&t;
      }
      uint4 tb = lB[((cgl + g) * 4 + k0) * 64 + lane];
      bv[g] = *(const short8*)&tb;
    }
#pragma unroll
    for (int mg = 0; mg < 4; ++mg)
#pragma unroll
      for (int ng = 0; ng < 4; ++ng)
        acc[mg][ng] = __builtin_amdgcn_mfma_f32_16x16x32_bf16(bv[ng], av[mg], acc[mg][ng], 0, 0, 0);
  }
  __syncthreads();                       // all waves done reading lB (lo)

  // ---- hi half ----
#pragma unroll
  for (int g = 0; g < 4; ++g) {          // prefetch A-hi k0=0
    uint4 t = AH[aB + (size_t)(g * 4) * 64];
    avp[g] = *(const short8*)&t;
  }
#pragma unroll
  for (int i = 0; i < 8; ++i)            // stage B-hi
    lB[i * 256 + tid] = BH[i * 256 + tid];
  __syncthreads();

#pragma unroll
  for (int k0 = 0; k0 < 4; ++k0) {
    short8 av[4], bv[4];
#pragma unroll
    for (int g = 0; g < 4; ++g) {
      if (k0 == 0) av[g] = avp[g];
      else {
        uint4 t = AH[aB + (size_t)(g * 4 + k0) * 64];
        av[g] = *(const short8*)&t;
      }
      uint4 tb = lB[((cgl + g) * 4 + k0) * 64 + lane];
      bv[g] = *(const short8*)&tb;
    }
#pragma unroll
    for (int mg = 0; mg < 4; ++mg)
#pragma unroll
      for (int ng = 0; ng < 4; ++ng)
        acc[mg][ng] = __builtin_amdgcn_mfma_f32_16x16x32_bf16(bv[ng], av[mg], acc[mg][ng], 0, 0, 0);
  }

  // ---- epilogue ----
#pragma unroll
  for (int mg = 0; mg < 4; ++mg) {
    int row = m0 + mg * 16 + r16;
    if (row < P.M) {
#pragma unroll
      for (int ng = 0; ng < 4; ++ng) {
        int col = n0 + ng * 16 + quad * 4;   // 4 consecutive cols in regs
        f32x4 v = acc[mg][ng];
        if (P.bias) {
          f32x4 b4 = *(const f32x4*)(P.bias + col);
          v += b4;
        }
        if (P.Madd) {
          uint2 md = *(const uint2*)(P.Madd + (size_t)row * 128 + col);
          v[0] += bf2f((unsigned short)(md.x & 0xffff));
          v[1] += bf2f((unsigned short)(md.x >> 16));
          v[2] += bf2f((unsigned short)(md.y & 0xffff));
          v[3] += bf2f((unsigned short)(md.y >> 16));
        }
        if (doRelu) {
          v[0] = fmaxf(v[0], 0.0f); v[1] = fmaxf(v[1], 0.0f);
          v[2] = fmaxf(v[2], 0.0f); v[3] = fmaxf(v[3], 0.0f);
        }
        if (outF32) {
          *(f32x4*)((float*)P.outp + (size_t)row * N + col) = v;
        } else {
          uint2 o;
          o.x = pack2(v[0], v[1]);
          o.y = pack2(v[2], v[3]);
          if (outFrag) {
            if (col < 128) *(uint2*)((unsigned short*)P.outp + fragS128(row, col)) = o;
            else           *(uint2*)(P.outHi + fragS128(row, col - 128)) = o;
          } else {
            *(uint2*)((unsigned short*)P.outp + (size_t)row * N + col) = o;
          }
        }
      }
    }
  }
}

// ---------------------------------------------------------------------------
extern "C" void kernel_launch(void* const* d_in, const int* in_sizes, int n_in,
                              void* d_out, int out_size, void* d_ws, size_t ws_size,
                              hipStream_t stream)
{
  const float* x_user  = (const float*)d_in[0];
  const float* x_item  = (const float*)d_in[1];
  const int*   esrc    = (const int*)d_in[2];
  const int*   edst    = (const int*)d_in[3];
  const float* W_l1_ui = (const float*)d_in[4];
  const float* W_r1_ui = (const float*)d_in[5];
  const float* b_l1_ui = (const float*)d_in[6];
  const float* W_l1_iu = (const float*)d_in[7];
  const float* W_r1_iu = (const float*)d_in[8];
  const float* b_l1_iu = (const float*)d_in[9];
  const float* W_l2_ui = (const float*)d_in[10];
  const float* W_r2_ui = (const float*)d_in[11];
  const float* b_l2_ui = (const float*)d_in[12];
  const float* W_l2_iu = (const float*)d_in[13];
  const float* W_r2_iu = (const float*)d_in[14];
  const float* b_l2_iu = (const float*)d_in[15];

  const int NU = in_sizes[0] / 128;   // 200000
  const int NI = in_sizes[1] / 128;   // 100000
  const int E  = in_sizes[2];         // 500000
  const int NA = NI + NU;
  const int MI = ((NI + 127) / 128) * 128;   // padded row counts
  const int MU = ((NU + 127) / 128) * 128;

  char* ws = (char*)d_ws;
  size_t off = 0;
  auto alloc = [&](size_t bytes) -> void* {
    void* p = ws + off;
    off += (bytes + 255) & ~(size_t)255;
    return p;
  };

  // --- zeroed-every-launch region ---
  int* cntAll = (int*)alloc((size_t)NA * 4);
  int* curAll = (int*)alloc((size_t)NA * 4);
  size_t zeroBytes = off;
  // --- CSR ---
  int* offAll   = (int*)alloc((size_t)(NA + 1) * 4);
  int* tileSums = (int*)alloc(256 * 4);
  int* idxAll   = (int*)alloc((size_t)2 * E * 4);
  // --- weights (bf16, frag128 split) ---
  unsigned short* T1ui_l  = (unsigned short*)alloc(256 * 128 * 2);
  unsigned short* T1ui_h  = (unsigned short*)alloc(256 * 128 * 2);
  unsigned short* T1iu_l  = (unsigned short*)alloc(256 * 128 * 2);
  unsigned short* T1iu_h  = (unsigned short*)alloc(256 * 128 * 2);
  unsigned short* T2lui_l = (unsigned short*)alloc(128 * 128 * 2);
  unsigned short* T2lui_h = (unsigned short*)alloc(128 * 128 * 2);
  unsigned short* T2rui_l = (unsigned short*)alloc(128 * 128 * 2);
  unsigned short* T2rui_h = (unsigned short*)alloc(128 * 128 * 2);
  unsigned short* T2liu_l = (unsigned short*)alloc(128 * 128 * 2);
  unsigned short* T2liu_h = (unsigned short*)alloc(128 * 128 * 2);
  unsigned short* T2riu_l = (unsigned short*)alloc(128 * 128 * 2);
  unsigned short* T2riu_h = (unsigned short*)alloc(128 * 128 * 2);
  // --- hidden states (frag128 split lo|hi, padded rows) ---
  unsigned short* h_item = (unsigned short*)alloc((size_t)MI * 256 * 2);
  unsigned short* h_item_hi = h_item + (size_t)MI * 128;
  unsigned short* h_user = (unsigned short*)alloc((size_t)MU * 256 * 2);
  unsigned short* h_user_hi = h_user + (size_t)MU * 128;
  // --- time-shared region R ---
  char* R = (char*)alloc((size_t)(MI + MU) * 256 * 2);
  // layer-1 phase: [Mf_item | Mf_user | Xf_item | Xf_user], each M*128 bf16
  unsigned short* Mf_item = (unsigned short*)R;
  unsigned short* Mf_user = (unsigned short*)(R + (size_t)MI * 128 * 2);
  unsigned short* Xf_item = (unsigned short*)(R + (size_t)(MI + MU) * 128 * 2);
  unsigned short* Xf_user = (unsigned short*)(R + (size_t)(2 * MI + MU) * 128 * 2);
  // layer-2 phase (layer-1 temporaries dead after L1 GEMMs); row-major:
  unsigned short* p_user = (unsigned short*)R;                                    // NU*128 bf16
  unsigned short* p_item = (unsigned short*)(R + (size_t)NU * 128 * 2);           // NI*128 bf16
  unsigned short* m2I    = (unsigned short*)(R + (size_t)(NU + NI) * 128 * 2);    // NI*128 bf16
  unsigned short* m2U    = (unsigned short*)(R + (size_t)(NU + 2 * NI) * 128 * 2);// NU*128 bf16

  float* out = (float*)d_out;   // [o_user (NU*128) | o_item (NI*128)] fp32

  // 1) zero counts/cursors
  hipMemsetAsync(ws, 0, zeroBytes, stream);

  // 2) weight transposes -> frag128 split (single launch)
  build_wt_all<<<1024, 256, 0, stream>>>(
      W_l1_ui, W_r1_ui, W_l1_iu, W_r1_iu, W_l2_ui, W_r2_ui, W_l2_iu, W_r2_iu,
      T1ui_l, T1ui_h, T1iu_l, T1iu_h,
      T2lui_l, T2lui_h, T2rui_l, T2rui_h, T2liu_l, T2liu_h, T2riu_l, T2riu_h);

  // 3) streaming self-feature conversion -> Xfrag (independent of CSR)
  int units = (MI + MU) * 16;
  conv_x<<<(units + 255) / 256, 256, 0, stream>>>(
      x_user, x_item, (uint4*)Xf_item, (uint4*)Xf_user, NI, NU, MI, MU);

  // 4) CSR build: hist -> 3-pass scan -> fill
  int egrid = (E + 255) / 256;
  int nTiles = (NA + SCAN_TILE - 1) / SCAN_TILE;
  hist<<<egrid, 256, 0, stream>>>(esrc, edst, cntAll, NI, E);
  scan_p1<<<nTiles, 256, 0, stream>>>(cntAll, tileSums, NA);
  scan_p2<<<1, 256, 0, stream>>>(tileSums, nTiles, offAll + NA);
  scan_p3<<<nTiles, 256, 0, stream>>>(cntAll, tileSums, offAll, NA);
  fill_idx<<<egrid, 256, 0, stream>>>(esrc, edst, offAll, curAll, idxAll, NI, E);

  // 5) layer-1 neighbor means -> Mfrag (gather-only, 2 nodes/wave)
  int waves1 = (NA + 1) / 2;
  build_mean<<<(waves1 * 64 + 255) / 256, 256, 0, stream>>>(
      x_user, x_item, idxAll, offAll, Mf_item, Mf_user, NI, NA);

  const int rbI = MI / 128, rbU = MU / 128;

  // 6) layer-1 GEMMs (merged): h = relu([mean@Wl] + [x@Wr] + b), frag128 out
  GemmP l1i = {Mf_item, Xf_item, T1ui_l, T1ui_h, b_l1_ui, nullptr, h_item, h_item_hi, NI};
  GemmP l1u = {Mf_user, Xf_user, T1iu_l, T1iu_h, b_l1_iu, nullptr, h_user, h_user_hi, NU};
  gemm_flat<<<dim3(rbI + rbU, 2), 256, 0, stream>>>(l1i, l1u, rbI, 0, 1, 256, 1);

  // 7) layer-2 left-projections (merged): p = h @ W_l2, row-major bf16
  GemmP pi = {h_item, h_item_hi, T2liu_l, T2liu_h, nullptr, nullptr, p_item, nullptr, NI};
  GemmP pu = {h_user, h_user_hi, T2lui_l, T2lui_h, nullptr, nullptr, p_user, nullptr, NU};
  gemm_flat<<<dim3(rbI + rbU, 1), 256, 0, stream>>>(pi, pu, rbI, 0, 0, 128, 0);

  // 8) layer-2 aggregation (4 nodes/wave)
  int waves2 = (NA + 3) / 4;
  seg_mean<<<(waves2 * 64 + 255) / 256, 256, 0, stream>>>(
      (const unsigned int*)p_user, (const unsigned int*)p_item,
      idxAll, offAll, (unsigned int*)m2I, (unsigned int*)m2U, NI, NA);

  // 9) output GEMMs (merged): o = relu(h @ W_r2 + m2 + b), fp32 out
  GemmP oi = {h_item, h_item_hi, T2rui_l, T2rui_h, b_l2_ui, m2I,
              out + (size_t)NU * 128, nullptr, NI};
  GemmP ou = {h_user, h_user_hi, T2riu_l, T2riu_h, b_l2_iu, m2U,
              out, nullptr, NU};
  gemm_flat<<<dim3(rbI + rbU, 1), 256, 0, stream>>>(oi, ou, rbI, 1, 0, 128, 1);
}

// Round 7
// 815.652 us; speedup vs baseline: 1.0659x; 1.0659x over previous
//
#include <hip/hip_runtime.h>
#include <stdint.h>

typedef __attribute__((ext_vector_type(8))) short short8;
typedef __attribute__((ext_vector_type(4))) float f32x4;

#define SCAN_TILE 4096

__device__ __forceinline__ float bf2f(unsigned short u) {
  union { unsigned int i; float f; } v;
  v.i = ((unsigned int)u) << 16;
  return v.f;
}
__device__ __forceinline__ unsigned short f2bf(float f) {
  union { float f; unsigned int i; } v;
  v.f = f;
  unsigned int u = v.i;
  return (unsigned short)((u + 0x7FFFu + ((u >> 16) & 1u)) >> 16);
}
__device__ __forceinline__ unsigned int pack2(float a, float b) {
  return (unsigned int)f2bf(a) | ((unsigned int)f2bf(b) << 16);
}
__device__ __forceinline__ void add2(float& a, float& b, unsigned int v) {
  a += bf2f((unsigned short)(v & 0xffff));
  b += bf2f((unsigned short)(v >> 16));
}

// ---------------------------------------------------------------------------
// MFMA fragment layout for [rows, K=128] bf16 matrices.
// chunk = (row/16)*4 + (k/32), each chunk = 1KB (64 lanes x 16B).
// slot within chunk = (row%16) + 16*((k%32)/8); (k%8) indexes inside 16B.
// A wave load of one fragment = uint4 at [chunk*64 + lane] -> 1KB coalesced.
// ---------------------------------------------------------------------------
__device__ __forceinline__ size_t fragS128(int row, int k) {
  return ((size_t)(row >> 4) * 4 + (size_t)(k >> 5)) * 512
       + (size_t)((((row & 15) + (((k >> 3) & 3) << 4)) << 3) + (k & 7));
}

// ---------------------------------------------------------------------------
// Weight transposes (fp32 -> bf16, [K,N] -> frag128 split lo/hi) in one launch.
// ---------------------------------------------------------------------------
__global__ __launch_bounds__(256) void build_wt_all(
    const float* __restrict__ Wl1ui, const float* __restrict__ Wr1ui,
    const float* __restrict__ Wl1iu, const float* __restrict__ Wr1iu,
    const float* __restrict__ Wl2ui, const float* __restrict__ Wr2ui,
    const float* __restrict__ Wl2iu, const float* __restrict__ Wr2iu,
    unsigned short* __restrict__ T1ui_l, unsigned short* __restrict__ T1ui_h,
    unsigned short* __restrict__ T1iu_l, unsigned short* __restrict__ T1iu_h,
    unsigned short* __restrict__ T2lui_l, unsigned short* __restrict__ T2lui_h,
    unsigned short* __restrict__ T2rui_l, unsigned short* __restrict__ T2rui_h,
    unsigned short* __restrict__ T2liu_l, unsigned short* __restrict__ T2liu_h,
    unsigned short* __restrict__ T2riu_l, unsigned short* __restrict__ T2riu_h)
{
  int idx = blockIdx.x * 256 + threadIdx.x;
  const float *W1, *W2;
  unsigned short *lo, *hi;
  int N, rel;
  if (idx < 65536)       { W1 = Wl1ui; W2 = Wr1ui;          lo = T1ui_l;  hi = T1ui_h;  N = 256; rel = idx; }
  else if (idx < 131072) { W1 = Wl1iu; W2 = Wr1iu;          lo = T1iu_l;  hi = T1iu_h;  N = 256; rel = idx - 65536; }
  else if (idx < 163840) { W1 = Wl2ui; W2 = Wl2ui + 128*128; lo = T2lui_l; hi = T2lui_h; N = 128; rel = idx - 131072; }
  else if (idx < 196608) { W1 = Wr2ui; W2 = Wr2ui + 128*128; lo = T2rui_l; hi = T2rui_h; N = 128; rel = idx - 163840; }
  else if (idx < 229376) { W1 = Wl2iu; W2 = Wl2iu + 128*128; lo = T2liu_l; hi = T2liu_h; N = 128; rel = idx - 196608; }
  else                   { W1 = Wr2iu; W2 = Wr2iu + 128*128; lo = T2riu_l; hi = T2riu_h; N = 128; rel = idx - 229376; }
  int n = rel >> 8;        // output-col index (B-frag row)
  int k = rel & 255;       // concat K index
  float v = (k < 128) ? W1[(size_t)k * N + n] : W2[(size_t)(k - 128) * N + n];
  if (k < 128) lo[fragS128(n, k)] = f2bf(v);
  else         hi[fragS128(n, k - 128)] = f2bf(v);
}

// ---------------------------------------------------------------------------
// Streaming fp32 -> bf16 frag128 conversion of self-features (x_item, x_user).
// ---------------------------------------------------------------------------
__global__ __launch_bounds__(256) void conv_x(
    const float* __restrict__ xu, const float* __restrict__ xi,
    uint4* __restrict__ XfI, uint4* __restrict__ XfU,
    int NI, int NU, int MI, int MU)
{
  int u = blockIdx.x * 256 + threadIdx.x;
  int unitsI = MI * 16;
  const float* x; uint4* Xf; int M; int rel;
  if (u < unitsI) { x = xi; Xf = XfI; M = NI; rel = u; }
  else {
    rel = u - unitsI;
    if (rel >= MU * 16) return;
    x = xu; Xf = XfU; M = NU;
  }
  int c = rel >> 6;                      // chunk
  int s = rel & 63;                      // 16B slot in chunk
  int row = ((c >> 2) << 4) + (s & 15);
  int k = ((c & 3) << 5) + ((s >> 4) << 3);
  uint4 o = make_uint4(0u, 0u, 0u, 0u);
  if (row < M) {
    f32x4 a = *(const f32x4*)(x + (size_t)row * 128 + k);
    f32x4 b = *(const f32x4*)(x + (size_t)row * 128 + k + 4);
    o.x = pack2(a[0], a[1]); o.y = pack2(a[2], a[3]);
    o.z = pack2(b[0], b[1]); o.w = pack2(b[2], b[3]);
  }
  Xf[rel] = o;
}

// ---------------------------------------------------------------------------
// CSR build over COMBINED node space (items [0,NI), users [NI,NI+NU)).
// ---------------------------------------------------------------------------
__global__ __launch_bounds__(256) void hist(
    const int* __restrict__ esrc, const int* __restrict__ edst,
    int* __restrict__ cntAll, int NI, int E)
{
  int e = blockIdx.x * 256 + threadIdx.x;
  if (e >= E) return;
  atomicAdd(&cntAll[edst[e]], 1);
  atomicAdd(&cntAll[NI + esrc[e]], 1);
}

__global__ __launch_bounds__(256) void scan_p1(
    const int* __restrict__ cnt, int* __restrict__ tileSums, int NA)
{
  __shared__ int red[256];
  int b = blockIdx.x, t = threadIdx.x;
  int base = b * SCAN_TILE;
  int s = 0;
  for (int i = t; i < SCAN_TILE; i += 256) {
    int g = base + i;
    if (g < NA) s += cnt[g];
  }
  red[t] = s;
  __syncthreads();
  for (int d = 128; d > 0; d >>= 1) {
    if (t < d) red[t] += red[t + d];
    __syncthreads();
  }
  if (t == 0) tileSums[b] = red[0];
}

__global__ __launch_bounds__(256) void scan_p2(
    int* __restrict__ tileSums, int nTiles, int* __restrict__ offEnd)
{
  __shared__ int buf[256];
  int t = threadIdx.x;
  int v = (t < nTiles) ? tileSums[t] : 0;
  buf[t] = v;
  __syncthreads();
  for (int d = 1; d < 256; d <<= 1) {
    int x = (t >= d) ? buf[t - d] : 0;
    __syncthreads();
    buf[t] += x;
    __syncthreads();
  }
  if (t < nTiles) tileSums[t] = buf[t] - v;   // exclusive
  if (t == nTiles - 1) *offEnd = buf[t];      // grand total -> offAll[NA]
}

__global__ __launch_bounds__(256) void scan_p3(
    const int* __restrict__ cnt, const int* __restrict__ tileSums,
    int* __restrict__ off, int NA)
{
  __shared__ int red[256];
  int b = blockIdx.x, t = threadIdx.x;
  int base = b * SCAN_TILE + t * 16;
  int loc[16];
  int s = 0;
#pragma unroll
  for (int i = 0; i < 16; ++i) {
    int g = base + i;
    loc[i] = (g < NA) ? cnt[g] : 0;
    s += loc[i];
  }
  red[t] = s;
  __syncthreads();
  for (int d = 1; d < 256; d <<= 1) {
    int x = (t >= d) ? red[t - d] : 0;
    __syncthreads();
    red[t] += x;
    __syncthreads();
  }
  int run = tileSums[b] + red[t] - s;  // exclusive base for this thread
#pragma unroll
  for (int i = 0; i < 16; ++i) {
    int g = base + i;
    if (g < NA) off[g] = run;
    run += loc[i];
  }
}

__global__ __launch_bounds__(256) void fill_idx(
    const int* __restrict__ esrc, const int* __restrict__ edst,
    const int* __restrict__ offAll, int* __restrict__ curAll,
    int* __restrict__ idxAll, int NI, int E)
{
  int e = blockIdx.x * 256 + threadIdx.x;
  if (e >= E) return;
  int s = esrc[e], d = edst[e];
  int pI = offAll[d] + atomicAdd(&curAll[d], 1);
  idxAll[pI] = s;                     // item d aggregates user rows
  int pU = offAll[NI + s] + atomicAdd(&curAll[NI + s], 1);
  idxAll[pU] = d;                     // user s aggregates item rows
}

// ---------------------------------------------------------------------------
// Layer-1 neighbor mean, one 32-lane HALF per node (2 nodes/wave).
// ---------------------------------------------------------------------------
__global__ __launch_bounds__(256) void build_mean(
    const float* __restrict__ xu, const float* __restrict__ xi,
    const int* __restrict__ idxAll, const int* __restrict__ offAll,
    unsigned short* __restrict__ MfI, unsigned short* __restrict__ MfU,
    int NI, int NA)
{
  int w2 = (blockIdx.x * 256 + threadIdx.x) >> 6;   // wave id
  int l = threadIdx.x & 63;
  int h = l >> 5;                          // half id (0/1)
  int lh = l & 31;                         // lane within half
  int node = w2 * 2 + h;
  if (node >= NA) return;
  bool isItem = (node < NI);
  const float* xo = isItem ? xu : xi;      // neighbor features
  unsigned short* Mf = isItem ? MfI : MfU;
  int n = isItem ? node : (node - NI);
  int s = offAll[node], e = offAll[node + 1];

  f32x4 acc = (f32x4){0.f, 0.f, 0.f, 0.f};
  int j = s;
  for (; j + 1 < e; j += 2) {              // 2 rows in flight per half
    int g0 = idxAll[j];
    int g1 = idxAll[j + 1];
    f32x4 v0 = *(const f32x4*)(xo + (size_t)g0 * 128 + lh * 4);
    f32x4 v1 = *(const f32x4*)(xo + (size_t)g1 * 128 + lh * 4);
    acc += v0 + v1;
  }
  if (j < e) {
    int g = idxAll[j];
    acc += *(const f32x4*)(xo + (size_t)g * 128 + lh * 4);
  }

  float inv = 1.0f / (float)max(e - s, 1);
  uint2 o;
  o.x = pack2(acc[0] * inv, acc[1] * inv);
  o.y = pack2(acc[2] * inv, acc[3] * inv);
  *(uint2*)(Mf + fragS128(n, lh * 4)) = o;
}

// ---------------------------------------------------------------------------
// Layer-2 aggregation: one 16-lane QUARTER per node (4 nodes/wave).
// ---------------------------------------------------------------------------
__global__ __launch_bounds__(256) void seg_mean(
    const unsigned int* __restrict__ pU, const unsigned int* __restrict__ pI,
    const int* __restrict__ idxAll, const int* __restrict__ offAll,
    unsigned int* __restrict__ m2I, unsigned int* __restrict__ m2U,
    int NI, int NA)
{
  int w4 = (blockIdx.x * 256 + threadIdx.x) >> 6;
  int l = threadIdx.x & 63;
  int q = l >> 4;                          // quarter id (0..3)
  int lq = l & 15;                         // lane within quarter
  int node = w4 * 4 + q;
  if (node >= NA) return;
  bool isItem = (node < NI);
  const unsigned int* p = isItem ? pU : pI;
  unsigned int* m2 = isItem ? m2I : m2U;
  int n = isItem ? node : (node - NI);
  int s = offAll[node], e = offAll[node + 1];

  float a0 = 0.f, a1 = 0.f, a2 = 0.f, a3 = 0.f,
        a4 = 0.f, a5 = 0.f, a6 = 0.f, a7 = 0.f;

  int j = s;
  for (; j + 1 < e; j += 2) {              // 2 rows in flight per quarter
    int g0 = idxAll[j];
    int g1 = idxAll[j + 1];
    uint4 v0 = *(const uint4*)(p + (size_t)g0 * 64 + lq * 4);
    uint4 v1 = *(const uint4*)(p + (size_t)g1 * 64 + lq * 4);
    add2(a0, a1, v0.x); add2(a2, a3, v0.y); add2(a4, a5, v0.z); add2(a6, a7, v0.w);
    add2(a0, a1, v1.x); add2(a2, a3, v1.y); add2(a4, a5, v1.z); add2(a6, a7, v1.w);
  }
  if (j < e) {
    int g = idxAll[j];
    uint4 v = *(const uint4*)(p + (size_t)g * 64 + lq * 4);
    add2(a0, a1, v.x); add2(a2, a3, v.y); add2(a4, a5, v.z); add2(a6, a7, v.w);
  }

  float inv = 1.0f / (float)max(e - s, 1);
  uint4 o;
  o.x = pack2(a0 * inv, a1 * inv);
  o.y = pack2(a2 * inv, a3 * inv);
  o.z = pack2(a4 * inv, a5 * inv);
  o.w = pack2(a6 * inv, a7 * inv);
  *(uint4*)(m2 + (size_t)n * 64 + lq * 4) = o;
}

// ---------------------------------------------------------------------------
// Deep-prefetch flat GEMM, K = 128+128 (split frag128 operands).
// Per block: issue ALL 16 A-lo fragment loads + stage B-lo to LDS, issue
// ALL 16 A-hi loads, then raw (lgkmcnt-only) barrier -- A-hi loads stay in
// flight across MFMA-lo. B-hi re-fetched from L2 (64KB, shared by all
// blocks -> L2-hot) after MFMA-lo. ~32KB of loads in flight per wave.
// __launch_bounds__(256,2): <=256 unified regs, 2 blocks/CU (LDS 64KB).
// MFMA operands swapped (mfma(b,a,acc)) -> lane holds row=lane&15, 4
// consecutive cols per quad -> vectorized stores.
// ---------------------------------------------------------------------------
struct GemmP {
  const unsigned short* Alo; const unsigned short* Ahi;
  const unsigned short* Blo; const unsigned short* Bhi;
  const float* bias;
  const unsigned short* Madd;   // [M,128] row-major or null
  void* outp; unsigned short* outHi;
  int M;
};

__global__ __launch_bounds__(256, 2) void gemm_flat(
    GemmP P0, GemmP P1, int rb0,
    int outF32, int outFrag, int N, int doRelu)
{
  __shared__ uint4 lB[4096];   // 64 KB: B strip, lo [0,2048) hi [2048,4096)

  const int bx = blockIdx.x;
  const bool first = (bx < rb0);
  GemmP P = first ? P0 : P1;
  const int mb = first ? bx : bx - rb0;

  const int tid = threadIdx.x;
  const int lane = tid & 63;
  const int wave = tid >> 6;
  const int m0 = mb * 128 + (wave >> 1) * 64;          // wave's first row
  const int nBase = blockIdx.y * 128;
  const int n0 = nBase + (wave & 1) * 64;              // wave's first col
  const int r16 = lane & 15;
  const int quad = lane >> 4;
  const int cgl = (wave & 1) * 4;                      // wave's first local col-group

  const uint4* AL = (const uint4*)P.Alo;
  const uint4* AH = (const uint4*)P.Ahi;
  const uint4* BL = (const uint4*)P.Blo + (size_t)(nBase >> 4) * 256;
  const uint4* BH = (const uint4*)P.Bhi + (size_t)(nBase >> 4) * 256;
  const size_t aB = (size_t)(m0 >> 4) * 256 + lane;

  // B-lo -> regs (8 x uint4)
  uint4 bs[8];
#pragma unroll
  for (int i = 0; i < 8; ++i) bs[i] = BL[i * 256 + tid];

  // A-lo: all 16 fragments, k0-major issue order (k0=0 frags land first)
  uint4 alo[16];
#pragma unroll
  for (int k0 = 0; k0 < 4; ++k0)
#pragma unroll
    for (int g = 0; g < 4; ++g)
      alo[k0 * 4 + g] = AL[aB + (size_t)(g * 256 + k0 * 64)];

  // stage B-lo (compiler inserts vmcnt wait for bs only -- alo stays in flight)
#pragma unroll
  for (int i = 0; i < 8; ++i) lB[i * 256 + tid] = bs[i];

  // A-hi: issued now, in flight across the barrier and all of MFMA-lo
  uint4 ahi[16];
#pragma unroll
  for (int k0 = 0; k0 < 4; ++k0)
#pragma unroll
    for (int g = 0; g < 4; ++g)
      ahi[k0 * 4 + g] = AH[aB + (size_t)(g * 256 + k0 * 64)];

  // raw barrier: drain LDS writes only; does NOT drain vmcnt (A-hi prefetch)
  asm volatile("s_waitcnt lgkmcnt(0)\ns_barrier" ::: "memory");

  f32x4 acc[4][4];
#pragma unroll
  for (int i = 0; i < 4; ++i)
#pragma unroll
    for (int j = 0; j < 4; ++j) acc[i][j] = (f32x4){0.f, 0.f, 0.f, 0.f};

  // ---- MFMA lo ----
#pragma unroll
  for (int k0 = 0; k0 < 4; ++k0) {
    short8 bv[4];
#pragma unroll
    for (int g = 0; g < 4; ++g) {
      uint4 tb = lB[((cgl + g) * 4 + k0) * 64 + lane];
      bv[g] = *(const short8*)&tb;
    }
#pragma unroll
    for (int mg = 0; mg < 4; ++mg) {
      short8 av = *(const short8*)&alo[k0 * 4 + mg];
#pragma unroll
      for (int ng = 0; ng < 4; ++ng)
        acc[mg][ng] = __builtin_amdgcn_mfma_f32_16x16x32_bf16(bv[ng], av, acc[mg][ng], 0, 0, 0);
    }
  }

  // B-hi (64KB shared by all blocks -> L2-hot) -> regs -> LDS
#pragma unroll
  for (int i = 0; i < 8; ++i) bs[i] = BH[i * 256 + tid];
#pragma unroll
  for (int i = 0; i < 8; ++i) lB[2048 + i * 256 + tid] = bs[i];
  asm volatile("s_waitcnt lgkmcnt(0)\ns_barrier" ::: "memory");

  // ---- MFMA hi ----
#pragma unroll
  for (int k0 = 0; k0 < 4; ++k0) {
    short8 bv[4];
#pragma unroll
    for (int g = 0; g < 4; ++g) {
      uint4 tb = lB[2048 + ((cgl + g) * 4 + k0) * 64 + lane];
      bv[g] = *(const short8*)&tb;
    }
#pragma unroll
    for (int mg = 0; mg < 4; ++mg) {
      short8 av = *(const short8*)&ahi[k0 * 4 + mg];
#pragma unroll
      for (int ng = 0; ng < 4; ++ng)
        acc[mg][ng] = __builtin_amdgcn_mfma_f32_16x16x32_bf16(bv[ng], av, acc[mg][ng], 0, 0, 0);
    }
  }

  // ---- epilogue ----
#pragma unroll
  for (int mg = 0; mg < 4; ++mg) {
    int row = m0 + mg * 16 + r16;
    if (row < P.M) {
#pragma unroll
      for (int ng = 0; ng < 4; ++ng) {
        int col = n0 + ng * 16 + quad * 4;   // 4 consecutive cols in regs
        f32x4 v = acc[mg][ng];
        if (P.bias) {
          f32x4 b4 = *(const f32x4*)(P.bias + col);
          v += b4;
        }
        if (P.Madd) {
          uint2 md = *(const uint2*)(P.Madd + (size_t)row * 128 + col);
          v[0] += bf2f((unsigned short)(md.x & 0xffff));
          v[1] += bf2f((unsigned short)(md.x >> 16));
          v[2] += bf2f((unsigned short)(md.y & 0xffff));
          v[3] += bf2f((unsigned short)(md.y >> 16));
        }
        if (doRelu) {
          v[0] = fmaxf(v[0], 0.0f); v[1] = fmaxf(v[1], 0.0f);
          v[2] = fmaxf(v[2], 0.0f); v[3] = fmaxf(v[3], 0.0f);
        }
        if (outF32) {
          *(f32x4*)((float*)P.outp + (size_t)row * N + col) = v;
        } else {
          uint2 o;
          o.x = pack2(v[0], v[1]);
          o.y = pack2(v[2], v[3]);
          if (outFrag) {
            if (col < 128) *(uint2*)((unsigned short*)P.outp + fragS128(row, col)) = o;
            else           *(uint2*)(P.outHi + fragS128(row, col - 128)) = o;
          } else {
            *(uint2*)((unsigned short*)P.outp + (size_t)row * N + col) = o;
          }
        }
      }
    }
  }
}

// ---------------------------------------------------------------------------
extern "C" void kernel_launch(void* const* d_in, const int* in_sizes, int n_in,
                              void* d_out, int out_size, void* d_ws, size_t ws_size,
                              hipStream_t stream)
{
  const float* x_user  = (const float*)d_in[0];
  const float* x_item  = (const float*)d_in[1];
  const int*   esrc    = (const int*)d_in[2];
  const int*   edst    = (const int*)d_in[3];
  const float* W_l1_ui = (const float*)d_in[4];
  const float* W_r1_ui = (const float*)d_in[5];
  const float* b_l1_ui = (const float*)d_in[6];
  const float* W_l1_iu = (const float*)d_in[7];
  const float* W_r1_iu = (const float*)d_in[8];
  const float* b_l1_iu = (const float*)d_in[9];
  const float* W_l2_ui = (const float*)d_in[10];
  const float* W_r2_ui = (const float*)d_in[11];
  const float* b_l2_ui = (const float*)d_in[12];
  const float* W_l2_iu = (const float*)d_in[13];
  const float* W_r2_iu = (const float*)d_in[14];
  const float* b_l2_iu = (const float*)d_in[15];

  const int NU = in_sizes[0] / 128;   // 200000
  const int NI = in_sizes[1] / 128;   // 100000
  const int E  = in_sizes[2];         // 500000
  const int NA = NI + NU;
  const int MI = ((NI + 127) / 128) * 128;   // padded row counts
  const int MU = ((NU + 127) / 128) * 128;

  char* ws = (char*)d_ws;
  size_t off = 0;
  auto alloc = [&](size_t bytes) -> void* {
    void* p = ws + off;
    off += (bytes + 255) & ~(size_t)255;
    return p;
  };

  // --- zeroed-every-launch region ---
  int* cntAll = (int*)alloc((size_t)NA * 4);
  int* curAll = (int*)alloc((size_t)NA * 4);
  size_t zeroBytes = off;
  // --- CSR ---
  int* offAll   = (int*)alloc((size_t)(NA + 1) * 4);
  int* tileSums = (int*)alloc(256 * 4);
  int* idxAll   = (int*)alloc((size_t)2 * E * 4);
  // --- weights (bf16, frag128 split) ---
  unsigned short* T1ui_l  = (unsigned short*)alloc(256 * 128 * 2);
  unsigned short* T1ui_h  = (unsigned short*)alloc(256 * 128 * 2);
  unsigned short* T1iu_l  = (unsigned short*)alloc(256 * 128 * 2);
  unsigned short* T1iu_h  = (unsigned short*)alloc(256 * 128 * 2);
  unsigned short* T2lui_l = (unsigned short*)alloc(128 * 128 * 2);
  unsigned short* T2lui_h = (unsigned short*)alloc(128 * 128 * 2);
  unsigned short* T2rui_l = (unsigned short*)alloc(128 * 128 * 2);
  unsigned short* T2rui_h = (unsigned short*)alloc(128 * 128 * 2);
  unsigned short* T2liu_l = (unsigned short*)alloc(128 * 128 * 2);
  unsigned short* T2liu_h = (unsigned short*)alloc(128 * 128 * 2);
  unsigned short* T2riu_l = (unsigned short*)alloc(128 * 128 * 2);
  unsigned short* T2riu_h = (unsigned short*)alloc(128 * 128 * 2);
  // --- hidden states (frag128 split lo|hi, padded rows) ---
  unsigned short* h_item = (unsigned short*)alloc((size_t)MI * 256 * 2);
  unsigned short* h_item_hi = h_item + (size_t)MI * 128;
  unsigned short* h_user = (unsigned short*)alloc((size_t)MU * 256 * 2);
  unsigned short* h_user_hi = h_user + (size_t)MU * 128;
  // --- time-shared region R ---
  char* R = (char*)alloc((size_t)(MI + MU) * 256 * 2);
  // layer-1 phase: [Mf_item | Mf_user | Xf_item | Xf_user], each M*128 bf16
  unsigned short* Mf_item = (unsigned short*)R;
  unsigned short* Mf_user = (unsigned short*)(R + (size_t)MI * 128 * 2);
  unsigned short* Xf_item = (unsigned short*)(R + (size_t)(MI + MU) * 128 * 2);
  unsigned short* Xf_user = (unsigned short*)(R + (size_t)(2 * MI + MU) * 128 * 2);
  // layer-2 phase (layer-1 temporaries dead after L1 GEMMs); row-major:
  unsigned short* p_user = (unsigned short*)R;                                    // NU*128 bf16
  unsigned short* p_item = (unsigned short*)(R + (size_t)NU * 128 * 2);           // NI*128 bf16
  unsigned short* m2I    = (unsigned short*)(R + (size_t)(NU + NI) * 128 * 2);    // NI*128 bf16
  unsigned short* m2U    = (unsigned short*)(R + (size_t)(NU + 2 * NI) * 128 * 2);// NU*128 bf16

  float* out = (float*)d_out;   // [o_user (NU*128) | o_item (NI*128)] fp32

  // 1) zero counts/cursors
  hipMemsetAsync(ws, 0, zeroBytes, stream);

  // 2) weight transposes -> frag128 split (single launch)
  build_wt_all<<<1024, 256, 0, stream>>>(
      W_l1_ui, W_r1_ui, W_l1_iu, W_r1_iu, W_l2_ui, W_r2_ui, W_l2_iu, W_r2_iu,
      T1ui_l, T1ui_h, T1iu_l, T1iu_h,
      T2lui_l, T2lui_h, T2rui_l, T2rui_h, T2liu_l, T2liu_h, T2riu_l, T2riu_h);

  // 3) streaming self-feature conversion -> Xfrag (independent of CSR)
  int units = (MI + MU) * 16;
  conv_x<<<(units + 255) / 256, 256, 0, stream>>>(
      x_user, x_item, (uint4*)Xf_item, (uint4*)Xf_user, NI, NU, MI, MU);

  // 4) CSR build: hist -> 3-pass scan -> fill
  int egrid = (E + 255) / 256;
  int nTiles = (NA + SCAN_TILE - 1) / SCAN_TILE;
  hist<<<egrid, 256, 0, stream>>>(esrc, edst, cntAll, NI, E);
  scan_p1<<<nTiles, 256, 0, stream>>>(cntAll, tileSums, NA);
  scan_p2<<<1, 256, 0, stream>>>(tileSums, nTiles, offAll + NA);
  scan_p3<<<nTiles, 256, 0, stream>>>(cntAll, tileSums, offAll, NA);
  fill_idx<<<egrid, 256, 0, stream>>>(esrc, edst, offAll, curAll, idxAll, NI, E);

  // 5) layer-1 neighbor means -> Mfrag (gather-only, 2 nodes/wave)
  int waves1 = (NA + 1) / 2;
  build_mean<<<(waves1 * 64 + 255) / 256, 256, 0, stream>>>(
      x_user, x_item, idxAll, offAll, Mf_item, Mf_user, NI, NA);

  const int rbI = MI / 128, rbU = MU / 128;

  // 6) layer-1 GEMMs (merged): h = relu([mean@Wl] + [x@Wr] + b), frag128 out
  GemmP l1i = {Mf_item, Xf_item, T1ui_l, T1ui_h, b_l1_ui, nullptr, h_item, h_item_hi, NI};
  GemmP l1u = {Mf_user, Xf_user, T1iu_l, T1iu_h, b_l1_iu, nullptr, h_user, h_user_hi, NU};
  gemm_flat<<<dim3(rbI + rbU, 2), 256, 0, stream>>>(l1i, l1u, rbI, 0, 1, 256, 1);

  // 7) layer-2 left-projections (merged): p = h @ W_l2, row-major bf16
  GemmP pi = {h_item, h_item_hi, T2liu_l, T2liu_h, nullptr, nullptr, p_item, nullptr, NI};
  GemmP pu = {h_user, h_user_hi, T2lui_l, T2lui_h, nullptr, nullptr, p_user, nullptr, NU};
  gemm_flat<<<dim3(rbI + rbU, 1), 256, 0, stream>>>(pi, pu, rbI, 0, 0, 128, 0);

  // 8) layer-2 aggregation (4 nodes/wave)
  int waves2 = (NA + 3) / 4;
  seg_mean<<<(waves2 * 64 + 255) / 256, 256, 0, stream>>>(
      (const unsigned int*)p_user, (const unsigned int*)p_item,
      idxAll, offAll, (unsigned int*)m2I, (unsigned int*)m2U, NI, NA);

  // 9) output GEMMs (merged): o = relu(h @ W_r2 + m2 + b), fp32 out
  GemmP oi = {h_item, h_item_hi, T2rui_l, T2rui_h, b_l2_ui, m2I,
              out + (size_t)NU * 128, nullptr, NI};
  GemmP ou = {h_user, h_user_hi, T2riu_l, T2riu_h, b_l2_iu, m2U,
              out, nullptr, NU};
  gemm_flat<<<dim3(rbI + rbU, 1), 256, 0, stream>>>(oi, ou, rbI, 1, 0, 128, 1);
}